// Round 11
// baseline (3635.565 us; speedup 1.0000x reference)
//
#include <hip/hip_runtime.h>

#define BB 32
#define TT 512
#define DD 512
#define HH 1024
#define G4 4096   // 4*H
#define NWG 64
#define BLK 512
#define DPW 16    // h-dims per WG
#define HSLOT (BB * HH)   // one h ring slot (elements)

typedef __bf16 bf16x8 __attribute__((ext_vector_type(8)));
typedef float f32x4 __attribute__((ext_vector_type(4)));
typedef unsigned int u32x4 __attribute__((ext_vector_type(4)));
typedef unsigned short u16x4 __attribute__((ext_vector_type(4)));
typedef unsigned short u16x8 __attribute__((ext_vector_type(8)));
typedef unsigned long long u64;

__device__ __forceinline__ unsigned short f2b(float f) {
    unsigned u = __builtin_bit_cast(unsigned, f);
    u += 0x7fffu + ((u >> 16) & 1u);
    return (unsigned short)(u >> 16);
}
__device__ __forceinline__ float b2f(unsigned short s) {
    unsigned u = ((unsigned)s) << 16;
    return __builtin_bit_cast(float, u);
}

// ---------- Kernel 1: xp = bf16( X[B*T,D] @ Wi[D,4H] ), fp32 accum (R10, 128x128) ----------
__global__ __launch_bounds__(512) void xproj_gemm(const float* __restrict__ X,
                                                  const float* __restrict__ Wi,
                                                  unsigned short* __restrict__ xp)
{
    __shared__ unsigned short As[128][40];   // [m][k]
    __shared__ unsigned short Bs[128][40];   // [n][k] transposed
    const int nb = G4 / 128;
    const int m0 = (blockIdx.x / nb) * 128;
    const int n0 = (blockIdx.x % nb) * 128;
    const int tid = threadIdx.x;
    const int w = tid >> 6;
    const int lane = tid & 63;
    const int q = lane >> 4;
    const int l16 = lane & 15;
    const int wmRow = (w & 1) * 64;          // 2 m-tiles of 64 rows
    const int wn0 = (w >> 1) * 32;           // 4 n-tiles of 32 cols

    const int ar = tid >> 2, ac = (tid & 3) * 8;    // A: 128 rows x 32 k
    const int bk = tid >> 4, bn = (tid & 15) * 8;   // B: 32 k x 128 cols

    f32x4 acc[4][2] = {};

    for (int k0 = 0; k0 < DD; k0 += 32) {
        const float* ap = X + (size_t)(m0 + ar) * DD + k0 + ac;
        float4 a0 = *(const float4*)ap;
        float4 a1 = *(const float4*)(ap + 4);
        unsigned short* as = &As[ar][ac];
        as[0]=f2b(a0.x); as[1]=f2b(a0.y); as[2]=f2b(a0.z); as[3]=f2b(a0.w);
        as[4]=f2b(a1.x); as[5]=f2b(a1.y); as[6]=f2b(a1.z); as[7]=f2b(a1.w);
        const float* bp = Wi + (size_t)(k0 + bk) * G4 + n0 + bn;
        float4 b0 = *(const float4*)bp;
        float4 b1 = *(const float4*)(bp + 4);
        Bs[bn+0][bk]=f2b(b0.x); Bs[bn+1][bk]=f2b(b0.y); Bs[bn+2][bk]=f2b(b0.z); Bs[bn+3][bk]=f2b(b0.w);
        Bs[bn+4][bk]=f2b(b1.x); Bs[bn+5][bk]=f2b(b1.y); Bs[bn+6][bk]=f2b(b1.z); Bs[bn+7][bk]=f2b(b1.w);
        __syncthreads();
        bf16x8 af0 = *(const bf16x8*)&As[wmRow +  0 + l16][q*8];
        bf16x8 af1 = *(const bf16x8*)&As[wmRow + 16 + l16][q*8];
        bf16x8 af2 = *(const bf16x8*)&As[wmRow + 32 + l16][q*8];
        bf16x8 af3 = *(const bf16x8*)&As[wmRow + 48 + l16][q*8];
        bf16x8 bfr0 = *(const bf16x8*)&Bs[wn0 +  0 + l16][q*8];
        bf16x8 bfr1 = *(const bf16x8*)&Bs[wn0 + 16 + l16][q*8];
        acc[0][0] = __builtin_amdgcn_mfma_f32_16x16x32_bf16(af0, bfr0, acc[0][0], 0,0,0);
        acc[0][1] = __builtin_amdgcn_mfma_f32_16x16x32_bf16(af0, bfr1, acc[0][1], 0,0,0);
        acc[1][0] = __builtin_amdgcn_mfma_f32_16x16x32_bf16(af1, bfr0, acc[1][0], 0,0,0);
        acc[1][1] = __builtin_amdgcn_mfma_f32_16x16x32_bf16(af1, bfr1, acc[1][1], 0,0,0);
        acc[2][0] = __builtin_amdgcn_mfma_f32_16x16x32_bf16(af2, bfr0, acc[2][0], 0,0,0);
        acc[2][1] = __builtin_amdgcn_mfma_f32_16x16x32_bf16(af2, bfr1, acc[2][1], 0,0,0);
        acc[3][0] = __builtin_amdgcn_mfma_f32_16x16x32_bf16(af3, bfr0, acc[3][0], 0,0,0);
        acc[3][1] = __builtin_amdgcn_mfma_f32_16x16x32_bf16(af3, bfr1, acc[3][1], 0,0,0);
        __syncthreads();
    }
    #pragma unroll
    for (int i = 0; i < 4; i++)
        #pragma unroll
        for (int j = 0; j < 2; j++) {
            int R = m0 + wmRow + i*16 + q*4;
            int C = n0 + wn0 + j*16 + l16;
            int b = R >> 9;
            int t = R & 511;
            int g = C >> 10;
            int hd = C & (HH - 1);
            u16x4 v;
            v.x = f2b(acc[i][j][0]); v.y = f2b(acc[i][j][1]);
            v.z = f2b(acc[i][j][2]); v.w = f2b(acc[i][j][3]);
            size_t off = (((size_t)(b * HH + hd) * (TT/8) + (t >> 3)) * 4 + g) * 8 + (t & 7);
            *(u16x4*)(xp + off) = v;
        }
}

// ---------- Kernel 2: persistent LSTM scan, R10 protocol + DVFS HEATER ----------
// Five passing sync topologies (R0/R1/R3/R8/R10) spanning 64x contention
// differences all land at 5.3-9.5 us/step; cycle models predict 1-1.5 us at
// 2.4 GHz. One theory explains the uniform ~4-5x inflation: at 2% utilization
// the power governor drops clocks, inflating EVERY wall-clock latency leg.
// Experiment: during the poll phase, waves 1-7 (otherwise asleep at b1) run
// junk MFMA chains on breg, exiting via an LDS hint (ls_ep) that wave0 raises
// when its flag poll passes; wave0 interleaves junk MFMAs between flag loads.
// The REAL gate is unchanged (wave0 flag poll + __syncthreads) -> correctness
// structurally identical to R10 (passing). If DVFS is the floor, step time
// drops 6 -> ~3 us; if unchanged, the visibility floor is real -> roofline.
__global__ __launch_bounds__(BLK, 1) void lstm_seq(
    const unsigned short* __restrict__ xp,      // [B][H][T/8][4][8] bf16
    const int* __restrict__ lengths,
    const float* __restrict__ c0,
    const float* __restrict__ h0,
    const float* __restrict__ Wh,
    const float* __restrict__ bias,
    float* __restrict__ out,                    // outputs[B,T,H] | c_fin[B,H] | h_fin[B,H]
    unsigned short* __restrict__ hbuf,          // [T+1][B*H] bf16 ring
    int* __restrict__ flags)                    // [64] PACKED, host memset 0xff (=-1)
{
    __shared__ float gs[2][32][65];          // [khalf][batch][gate*16+dim]
    __shared__ int ls_ep;                    // heater-exit hint (NOT a correctness gate)
    const int wg = blockIdx.x;
    const int tid = threadIdx.x;
    const int lane = tid & 63;
    const int w = tid >> 6;                  // 0..7
    const int q = lane >> 4, l16 = lane & 15;

    const int Mt = (w & 1) * 16;             // batch tile
    const int kh = (w >> 1) & 1;             // K half
    const int cp = w >> 2;                   // col-tile pair: ct = cp*2 + cc
    const int kbase = kh * 512;

    if (tid == 0) ls_ep = -1;

    // ---- one-time: load this wave's 32 Wh B-fragments into registers ----
    bf16x8 breg[16][2];
    #pragma unroll
    for (int kk = 0; kk < 16; ++kk) {
        #pragma unroll
        for (int cc = 0; cc < 2; ++cc) {
            const int col = (cp*2 + cc) * HH + wg * DPW + l16;
            const int kb = kbase + kk*32 + q*8;
            u16x8 tv;
            #pragma unroll
            for (int e = 0; e < 8; ++e)
                tv[e] = f2b(Wh[(size_t)(kb + e) * G4 + col]);
            breg[kk][cc] = __builtin_bit_cast(bf16x8, tv);
        }
    }

    const int bb = tid >> 4, dd = tid & 15;  // all 512 threads do pointwise
    const int gdim = wg * DPW + dd;
    float c   = c0[bb * HH + gdim];
    const int len = lengths[bb];
    const float bi  = bias[0*HH + gdim];
    const float bfg = bias[1*HH + gdim];
    const float bgv = bias[2*HH + gdim];
    const float bo  = bias[3*HH + gdim];
    const size_t xrow = ((size_t)bb * HH + gdim) * (TT/8) * 32;

    // h0 init: 128 threads store this WG's slice (32 b x 16 dims = 128 quads).
    if (tid < 128) {
        int b2 = tid >> 2, j = (tid & 3) * 4;
        const float* hp0 = h0 + (size_t)b2 * HH + wg * DPW + j;
        unsigned lo = (unsigned)f2b(hp0[0]) | ((unsigned)f2b(hp0[1]) << 16);
        unsigned hi = (unsigned)f2b(hp0[2]) | ((unsigned)f2b(hp0[3]) << 16);
        u64 v = (u64)lo | ((u64)hi << 32);
        __hip_atomic_store((u64*)(hbuf + (size_t)b2 * HH + wg * DPW + j), v,
                           __ATOMIC_RELAXED, __HIP_MEMORY_SCOPE_AGENT);
    }
    __syncthreads();                  // vmcnt(0): init stores acked; ls_ep=-1 visible
    if (tid == 0)                     // publish slot 0 (plain store, no RMW)
        __hip_atomic_store(&flags[wg], 0, __ATOMIC_RELAXED, __HIP_MEMORY_SCOPE_AGENT);

    f32x4 junk = {0.f, 0.f, 0.f, 0.f};   // heater accumulator (kept live at end)
    int fv = -1;                      // wave0 per-lane cached flag of WG 'lane'
    for (int t0 = 0; t0 < TT; t0 += 8) {
        // Prefetch 8 steps x 4 gates of x-projection: one contiguous 64B chunk.
        const unsigned short* xc = xp + xrow + (size_t)(t0 >> 3) * 32;
        u32x4 xq0 = __builtin_nontemporal_load((const u32x4*)(xc + 0));
        u32x4 xq1 = __builtin_nontemporal_load((const u32x4*)(xc + 8));
        u32x4 xq2 = __builtin_nontemporal_load((const u32x4*)(xc + 16));
        u32x4 xq3 = __builtin_nontemporal_load((const u32x4*)(xc + 24));
        float hreg[8];
        #pragma unroll
        for (int dt = 0; dt < 8; ++dt) {
            const int t = t0 + dt;
            // ---- poll (wave0) with junk-MFMA heat; waves 1-7 heat on LDS hint ----
            if (w == 0) {
                int spins = 0;
                while (!__all(fv >= t)) {
                    fv = __hip_atomic_load(&flags[lane], __ATOMIC_RELAXED,
                                           __HIP_MEMORY_SCOPE_AGENT);
                    junk = __builtin_amdgcn_mfma_f32_16x16x32_bf16(breg[0][0], breg[1][1], junk, 0,0,0);
                    junk = __builtin_amdgcn_mfma_f32_16x16x32_bf16(breg[2][0], breg[3][1], junk, 0,0,0);
                    if (++spins > (1 << 20)) break;   // loud failure, never a hang
                }
                if (lane == 0)
                    *(volatile int*)&ls_ep = t;       // heater-exit hint only
            } else {
                int hspins = 0;
                while (*(volatile int*)&ls_ep < t) {  // stale read: keep heating
                    #pragma unroll
                    for (int u = 0; u < 8; ++u)
                        junk = __builtin_amdgcn_mfma_f32_16x16x32_bf16(
                            breg[u * 2][0], breg[u * 2 + 1][1], junk, 0,0,0);
                    if (++hspins > (1 << 18)) break;  // hint only; b1 is the gate
                }
            }
            __syncthreads();                                            // b1 (real gate)
            // ---- h slot t: plain cached loads (write-once slots; R0-proven) + MFMA ----
            const unsigned short* ha = hbuf + (size_t)t * HSLOT
                                     + (size_t)(Mt + l16) * HH + kbase + q*8;
            f32x4 acc0 = {0.f,0.f,0.f,0.f}, acc1 = {0.f,0.f,0.f,0.f};
            #pragma unroll
            for (int kk = 0; kk < 16; ++kk) {
                bf16x8 a = *(const bf16x8*)(ha + kk*32);
                acc0 = __builtin_amdgcn_mfma_f32_16x16x32_bf16(a, breg[kk][0], acc0, 0,0,0);
                acc1 = __builtin_amdgcn_mfma_f32_16x16x32_bf16(a, breg[kk][1], acc1, 0,0,0);
            }
            #pragma unroll
            for (int r = 0; r < 4; ++r) {
                gs[kh][Mt + q*4 + r][(cp*2+0)*16 + l16] = acc0[r];
                gs[kh][Mt + q*4 + r][(cp*2+1)*16 + l16] = acc1[r];
            }
            __syncthreads();                                            // b2
            // ---- pointwise (all 512 threads) ----
            const int wi = dt >> 1, sh = (dt & 1) * 16;
            float gi = gs[0][bb][ 0 + dd] + gs[1][bb][ 0 + dd] + b2f((unsigned short)(xq0[wi] >> sh)) + bi;
            float gf = gs[0][bb][16 + dd] + gs[1][bb][16 + dd] + b2f((unsigned short)(xq1[wi] >> sh)) + bfg;
            float gg = gs[0][bb][32 + dd] + gs[1][bb][32 + dd] + b2f((unsigned short)(xq2[wi] >> sh)) + bgv;
            float go = gs[0][bb][48 + dd] + gs[1][bb][48 + dd] + b2f((unsigned short)(xq3[wi] >> sh)) + bo;
            float si = 1.f / (1.f + __expf(-gi));
            float sf = 1.f / (1.f + __expf(-gf));
            float so = 1.f / (1.f + __expf(-go));
            float tg = 1.f - 2.f / (1.f + __expf(2.f * gg));
            c = sf * c + si * tg;
            float th = 1.f - 2.f / (1.f + __expf(2.f * c));
            float h = so * th;
            hreg[dt] = h;
            // Pack 4 bf16 h (dims 4-aligned) into u64 via shuffles; one store/quad.
            unsigned v = (unsigned)f2b(h);
            unsigned p1 = __shfl_xor(v, 1);
            unsigned pair = (dd & 1) ? (p1 | (v << 16)) : (v | (p1 << 16));
            unsigned p2 = __shfl_xor(pair, 2);
            u64 quad = (dd & 2) ? ((u64)p2 | ((u64)pair << 32))
                                : ((u64)pair | ((u64)p2 << 32));
            if ((dd & 3) == 0)
                __hip_atomic_store((u64*)(hbuf + (size_t)(t + 1) * HSLOT + (size_t)bb * HH + gdim),
                                   quad, __ATOMIC_RELAXED, __HIP_MEMORY_SCOPE_AGENT);
            if (t == len - 1) {       // rare: final states
                __builtin_nontemporal_store(c, &out[(size_t)BB*TT*HH + bb*HH + gdim]);
                __builtin_nontemporal_store(h, &out[(size_t)BB*TT*HH + (size_t)BB*HH + bb*HH + gdim]);
            }
            __syncthreads();          // b3: vmcnt(0) — h stores acked at coherence point
            if (tid == 0)             // publish slot t+1 (plain store, packed line)
                __hip_atomic_store(&flags[wg], t + 1,
                                   __ATOMIC_RELAXED, __HIP_MEMORY_SCOPE_AGENT);
            if (dt == 7) {
                // Flush 8 buffered h outputs AFTER the flag: HBM acks drain
                // during the next poll, off the critical path.
                #pragma unroll
                for (int j = 0; j < 8; ++j)
                    __builtin_nontemporal_store(hreg[j], &out[((size_t)bb * TT + t0 + j) * HH + gdim]);
            }
        }
    }
    // Keep the heater chain live (rule #17): sink junk so MFMAs aren't DCE'd.
    asm volatile("" :: "v"(junk[0]), "v"(junk[1]), "v"(junk[2]), "v"(junk[3]));
}

extern "C" void kernel_launch(void* const* d_in, const int* in_sizes, int n_in,
                              void* d_out, int out_size, void* d_ws, size_t ws_size,
                              hipStream_t stream)
{
    const float* X    = (const float*)d_in[0];
    const int*   lens = (const int*)d_in[1];
    const float* c0   = (const float*)d_in[2];
    const float* h0   = (const float*)d_in[3];
    const float* Wi   = (const float*)d_in[4];
    const float* Wh   = (const float*)d_in[5];
    const float* bias = (const float*)d_in[6];
    float* out = (float*)d_out;

    // ws layout: xp bf16 [B][H][T/8][4][8] (134.2 MB) | hbuf ring bf16 [T+1][B*H]
    //            (33.6 MB) | flags int[64] packed (256 B)
    unsigned short* xp   = (unsigned short*)d_ws;
    unsigned short* hbuf = xp + (size_t)BB * HH * TT * 4;
    int* flags = (int*)(hbuf + (size_t)(TT + 1) * HSLOT);

    // flags = -1: nobody passes the t=0 poll until h0 is published.
    (void)hipMemsetAsync(flags, 0xff, sizeof(int) * NWG, stream);

    xproj_gemm<<<dim3((BB*TT/128) * (G4/128)), dim3(512), 0, stream>>>(X, Wi, xp);

    const unsigned short* xp_c = xp;
    unsigned short* hbuf_p = hbuf;
    int* flags_p = flags;
    void* args[9];
    args[0] = (void*)&xp_c;
    args[1] = (void*)&lens;
    args[2] = (void*)&c0;
    args[3] = (void*)&h0;
    args[4] = (void*)&Wh;
    args[5] = (void*)&bias;
    args[6] = (void*)&out;
    args[7] = (void*)&hbuf_p;
    args[8] = (void*)&flags_p;
    (void)hipLaunchCooperativeKernel((void*)lstm_seq, dim3(NWG), dim3(BLK), args, 0, stream);
}

// Round 12
// 2275.312 us; speedup vs baseline: 1.5978x; 1.5978x over previous
//
#include <hip/hip_runtime.h>

#define BB 32
#define TT 512
#define DD 512
#define HH 1024
#define G4 4096   // 4*H
#define NWG 64
#define BLK 512
#define HSLOT (BB * HH)   // one h ring slot (elements)

typedef __bf16 bf16x8 __attribute__((ext_vector_type(8)));
typedef float f32x4 __attribute__((ext_vector_type(4)));
typedef unsigned int u32x4 __attribute__((ext_vector_type(4)));
typedef unsigned short u16x4 __attribute__((ext_vector_type(4)));
typedef unsigned short u16x8 __attribute__((ext_vector_type(8)));
typedef unsigned long long u64;

__device__ __forceinline__ unsigned short f2b(float f) {
    unsigned u = __builtin_bit_cast(unsigned, f);
    u += 0x7fffu + ((u >> 16) & 1u);
    return (unsigned short)(u >> 16);
}
__device__ __forceinline__ float b2f(unsigned short s) {
    unsigned u = ((unsigned)s) << 16;
    return __builtin_bit_cast(float, u);
}

// ---------- Kernel 1: xp = bf16( X[B*T,D] @ Wi[D,4H] ), fp32 accum (R10, 128x128) ----------
__global__ __launch_bounds__(512) void xproj_gemm(const float* __restrict__ X,
                                                  const float* __restrict__ Wi,
                                                  unsigned short* __restrict__ xp)
{
    __shared__ unsigned short As[128][40];   // [m][k]
    __shared__ unsigned short Bs[128][40];   // [n][k] transposed
    const int nb = G4 / 128;
    const int m0 = (blockIdx.x / nb) * 128;
    const int n0 = (blockIdx.x % nb) * 128;
    const int tid = threadIdx.x;
    const int w = tid >> 6;
    const int lane = tid & 63;
    const int q = lane >> 4;
    const int l16 = lane & 15;
    const int wmRow = (w & 1) * 64;          // 2 m-tiles of 64 rows
    const int wn0 = (w >> 1) * 32;           // 4 n-tiles of 32 cols

    const int ar = tid >> 2, ac = (tid & 3) * 8;    // A: 128 rows x 32 k
    const int bk = tid >> 4, bn = (tid & 15) * 8;   // B: 32 k x 128 cols

    f32x4 acc[4][2] = {};

    for (int k0 = 0; k0 < DD; k0 += 32) {
        const float* ap = X + (size_t)(m0 + ar) * DD + k0 + ac;
        float4 a0 = *(const float4*)ap;
        float4 a1 = *(const float4*)(ap + 4);
        unsigned short* as = &As[ar][ac];
        as[0]=f2b(a0.x); as[1]=f2b(a0.y); as[2]=f2b(a0.z); as[3]=f2b(a0.w);
        as[4]=f2b(a1.x); as[5]=f2b(a1.y); as[6]=f2b(a1.z); as[7]=f2b(a1.w);
        const float* bp = Wi + (size_t)(k0 + bk) * G4 + n0 + bn;
        float4 b0 = *(const float4*)bp;
        float4 b1 = *(const float4*)(bp + 4);
        Bs[bn+0][bk]=f2b(b0.x); Bs[bn+1][bk]=f2b(b0.y); Bs[bn+2][bk]=f2b(b0.z); Bs[bn+3][bk]=f2b(b0.w);
        Bs[bn+4][bk]=f2b(b1.x); Bs[bn+5][bk]=f2b(b1.y); Bs[bn+6][bk]=f2b(b1.z); Bs[bn+7][bk]=f2b(b1.w);
        __syncthreads();
        bf16x8 af0 = *(const bf16x8*)&As[wmRow +  0 + l16][q*8];
        bf16x8 af1 = *(const bf16x8*)&As[wmRow + 16 + l16][q*8];
        bf16x8 af2 = *(const bf16x8*)&As[wmRow + 32 + l16][q*8];
        bf16x8 af3 = *(const bf16x8*)&As[wmRow + 48 + l16][q*8];
        bf16x8 bfr0 = *(const bf16x8*)&Bs[wn0 +  0 + l16][q*8];
        bf16x8 bfr1 = *(const bf16x8*)&Bs[wn0 + 16 + l16][q*8];
        acc[0][0] = __builtin_amdgcn_mfma_f32_16x16x32_bf16(af0, bfr0, acc[0][0], 0,0,0);
        acc[0][1] = __builtin_amdgcn_mfma_f32_16x16x32_bf16(af0, bfr1, acc[0][1], 0,0,0);
        acc[1][0] = __builtin_amdgcn_mfma_f32_16x16x32_bf16(af1, bfr0, acc[1][0], 0,0,0);
        acc[1][1] = __builtin_amdgcn_mfma_f32_16x16x32_bf16(af1, bfr1, acc[1][1], 0,0,0);
        acc[2][0] = __builtin_amdgcn_mfma_f32_16x16x32_bf16(af2, bfr0, acc[2][0], 0,0,0);
        acc[2][1] = __builtin_amdgcn_mfma_f32_16x16x32_bf16(af2, bfr1, acc[2][1], 0,0,0);
        acc[3][0] = __builtin_amdgcn_mfma_f32_16x16x32_bf16(af3, bfr0, acc[3][0], 0,0,0);
        acc[3][1] = __builtin_amdgcn_mfma_f32_16x16x32_bf16(af3, bfr1, acc[3][1], 0,0,0);
        __syncthreads();
    }
    #pragma unroll
    for (int i = 0; i < 4; i++)
        #pragma unroll
        for (int j = 0; j < 2; j++) {
            int R = m0 + wmRow + i*16 + q*4;
            int C = n0 + wn0 + j*16 + l16;
            int b = R >> 9;
            int t = R & 511;
            int g = C >> 10;
            int hd = C & (HH - 1);
            u16x4 v;
            v.x = f2b(acc[i][j][0]); v.y = f2b(acc[i][j][1]);
            v.z = f2b(acc[i][j][2]); v.w = f2b(acc[i][j][3]);
            size_t off = (((size_t)(b * HH + hd) * (TT/8) + (t >> 3)) * 4 + g) * 8 + (t & 7);
            *(u16x4*)(xp + off) = v;
        }
}

// ---------- Kernel 2: persistent LSTM scan, TWO INDEPENDENT 32-WG GROUPS ----------
// R0-R11 eliminated contention, hop topology, data-poll, XCD-locality, DVFS as
// the ~6us/step cause. Surviving model: ~2us per MALL visibility hop x ~3 hops
// per rendezvous, PLUS the straggler tail of 64 globally-coupled WGs compounding
// over 512 steps. This round splits along the embarrassingly-parallel batch dim:
//   group g in {0,1} owns batches [16g,16g+16) and runs its own full-H
//   recurrence among its OWN 32 WGs. Rank r owns 32 h-dims (128 gate-cols);
//   wave w holds K-slice [w*128,(w+1)*128) x 128 cols in registers (128 VGPR,
//   M=16 = exact MFMA tile, zero redundancy, same total MFMA count as R10).
//   8 waves' K-partials reduce through LDS (R4's proven gsp pattern).
// Sync semantics = R10's PROVEN set verbatim: AGENT atomic flag stores (packed,
// per-group 128B line), wave0 wide-poll, plain-cached loads of write-once h
// slots, __syncthreads as coherence points. Each WG: half the h volume, half
// the flags, and the two pipelines drift independently (tails don't couple).
__global__ __launch_bounds__(BLK, 1) void lstm_seq(
    const unsigned short* __restrict__ xp,      // [B][H][T/8][4][8] bf16
    const int* __restrict__ lengths,
    const float* __restrict__ c0,
    const float* __restrict__ h0,
    const float* __restrict__ Wh,
    const float* __restrict__ bias,
    float* __restrict__ out,                    // outputs[B,T,H] | c_fin[B,H] | h_fin[B,H]
    unsigned short* __restrict__ hbuf,          // [T+1][B*H] bf16 ring
    int* __restrict__ flags)                    // [64] packed: g*32+r; memset 0xff (=-1)
{
    __shared__ float gsp[8][16][132];        // [wave][batch-in-group][gate*32+dim]
    const int wg = blockIdx.x;
    const int tid = threadIdx.x;
    const int lane = tid & 63;
    const int w = tid >> 6;                  // 0..7: K-slice [w*128,(w+1)*128)
    const int q = lane >> 4, l16 = lane & 15;

    const int gx = wg >> 5;                  // group 0/1 (batches 16gx..16gx+15)
    const int rk = wg & 31;                  // rank in group (dims rk*32..rk*32+31)
    const int d0 = rk * 32;

    // ---- one-time: wave w's Wh fragments: K rows [w*128,(w+1)*128), 128 cols ----
    // col-tile n: gate g=n>>1, dim j=(n&1)*16+l16 -> Wh col = g*1024 + d0 + j
    bf16x8 breg2[8][4];
    #pragma unroll
    for (int n = 0; n < 8; ++n) {
        const int col = (n >> 1) * HH + d0 + (n & 1) * 16 + l16;
        #pragma unroll
        for (int kk2 = 0; kk2 < 4; ++kk2) {
            const int kb = w * 128 + kk2 * 32 + q * 8;
            u16x8 tv;
            #pragma unroll
            for (int e = 0; e < 8; ++e)
                tv[e] = f2b(Wh[(size_t)(kb + e) * G4 + col]);
            breg2[n][kk2] = __builtin_bit_cast(bf16x8, tv);
        }
    }

    const int bb = tid >> 5;                 // batch-in-group 0..15
    const int dd = tid & 31;                 // dim-in-rank   0..31
    const int bbg = gx * 16 + bb;            // global batch
    const int gdim = d0 + dd;                // global h-dim
    float c   = c0[(size_t)bbg * HH + gdim];
    const int len = lengths[bbg];
    const float bi  = bias[0*HH + gdim];
    const float bfg = bias[1*HH + gdim];
    const float bgv = bias[2*HH + gdim];
    const float bo  = bias[3*HH + gdim];
    const size_t xrow = ((size_t)bbg * HH + gdim) * (TT/8) * 32;

    // h0 init: all 512 threads cover this WG's (16 batches x 32 dims) slice.
    {
        float hv = h0[(size_t)bbg * HH + gdim];
        unsigned v = (unsigned)f2b(hv);
        unsigned p1 = __shfl_xor(v, 1);
        unsigned pair = (dd & 1) ? (p1 | (v << 16)) : (v | (p1 << 16));
        unsigned p2 = __shfl_xor(pair, 2);
        u64 quad = (dd & 2) ? ((u64)p2 | ((u64)pair << 32))
                            : ((u64)pair | ((u64)p2 << 32));
        if ((dd & 3) == 0)
            __hip_atomic_store((u64*)(hbuf + (size_t)bbg * HH + gdim), quad,
                               __ATOMIC_RELAXED, __HIP_MEMORY_SCOPE_AGENT);
    }
    __syncthreads();                  // vmcnt(0): init stores acked at coherence point
    if (tid == 0)                     // publish slot 0 (plain store, packed group line)
        __hip_atomic_store(&flags[gx * 32 + rk], 0,
                           __ATOMIC_RELAXED, __HIP_MEMORY_SCOPE_AGENT);

    int fv = -1;                      // wave0: cached flag of group-rank (lane&31)
    for (int t0 = 0; t0 < TT; t0 += 8) {
        // Prefetch 8 steps x 4 gates of x-projection: one contiguous 64B chunk.
        const unsigned short* xc = xp + xrow + (size_t)(t0 >> 3) * 32;
        u32x4 xq0 = __builtin_nontemporal_load((const u32x4*)(xc + 0));
        u32x4 xq1 = __builtin_nontemporal_load((const u32x4*)(xc + 8));
        u32x4 xq2 = __builtin_nontemporal_load((const u32x4*)(xc + 16));
        u32x4 xq3 = __builtin_nontemporal_load((const u32x4*)(xc + 24));
        float hreg[8];
        #pragma unroll
        for (int dt = 0; dt < 8; ++dt) {
            const int t = t0 + dt;
            // ---- poll OWN GROUP's 32 packed flags (one 128B line) ----
            if (w == 0) {
                int spins = 0;
                while (!__all(fv >= t)) {
                    fv = __hip_atomic_load(&flags[gx * 32 + (lane & 31)],
                                           __ATOMIC_RELAXED, __HIP_MEMORY_SCOPE_AGENT);
                    if (++spins > (1 << 20)) break;   // loud failure, never a hang
                }
            }
            __syncthreads();                                            // b1
            // ---- A-frags: plain cached loads (write-once slots; R0-proven) ----
            // A row = batch-in-group (l16), K = w*128 + kk2*32 + q*8 + e.
            const unsigned short* ha = hbuf + (size_t)t * HSLOT
                                     + (size_t)(gx * 16 + l16) * HH + w * 128 + q * 8;
            bf16x8 afr[4];
            #pragma unroll
            for (int kk2 = 0; kk2 < 4; ++kk2)
                afr[kk2] = *(const bf16x8*)(ha + kk2 * 32);
            f32x4 acc[8] = {};
            #pragma unroll
            for (int n = 0; n < 8; ++n)
                #pragma unroll
                for (int kk2 = 0; kk2 < 4; ++kk2)
                    acc[n] = __builtin_amdgcn_mfma_f32_16x16x32_bf16(afr[kk2], breg2[n][kk2], acc[n], 0,0,0);
            // C/D: row = q*4+r = batch-in-group, col = l16 within col-tile n.
            #pragma unroll
            for (int n = 0; n < 8; ++n)
                #pragma unroll
                for (int r = 0; r < 4; ++r)
                    gsp[w][q*4 + r][(n >> 1) * 32 + (n & 1) * 16 + l16] = acc[n][r];
            __syncthreads();                                            // b2
            // ---- pointwise: all 512 threads (16 batches x 32 dims), sum 8 partials ----
            const int wi = dt >> 1, sh = (dt & 1) * 16;
            float gi = b2f((unsigned short)(xq0[wi] >> sh)) + bi;
            float gf = b2f((unsigned short)(xq1[wi] >> sh)) + bfg;
            float gg = b2f((unsigned short)(xq2[wi] >> sh)) + bgv;
            float go = b2f((unsigned short)(xq3[wi] >> sh)) + bo;
            #pragma unroll
            for (int ww = 0; ww < 8; ++ww) {
                gi += gsp[ww][bb][ 0 + dd];
                gf += gsp[ww][bb][32 + dd];
                gg += gsp[ww][bb][64 + dd];
                go += gsp[ww][bb][96 + dd];
            }
            float si = 1.f / (1.f + __expf(-gi));
            float sf = 1.f / (1.f + __expf(-gf));
            float so = 1.f / (1.f + __expf(-go));
            float tg = 1.f - 2.f / (1.f + __expf(2.f * gg));
            c = sf * c + si * tg;
            float th = 1.f - 2.f / (1.f + __expf(2.f * c));
            float h = so * th;
            hreg[dt] = h;
            // Pack 4 bf16 h (dims 4-aligned) into u64 via shuffles; one store/quad.
            unsigned v = (unsigned)f2b(h);
            unsigned p1 = __shfl_xor(v, 1);
            unsigned pair = (dd & 1) ? (p1 | (v << 16)) : (v | (p1 << 16));
            unsigned p2 = __shfl_xor(pair, 2);
            u64 quad = (dd & 2) ? ((u64)p2 | ((u64)pair << 32))
                                : ((u64)pair | ((u64)p2 << 32));
            if ((dd & 3) == 0)
                __hip_atomic_store((u64*)(hbuf + (size_t)(t + 1) * HSLOT + (size_t)bbg * HH + gdim),
                                   quad, __ATOMIC_RELAXED, __HIP_MEMORY_SCOPE_AGENT);
            if (t == len - 1) {       // rare: final states
                __builtin_nontemporal_store(c, &out[(size_t)BB*TT*HH + (size_t)bbg*HH + gdim]);
                __builtin_nontemporal_store(h, &out[(size_t)BB*TT*HH + (size_t)BB*HH + (size_t)bbg*HH + gdim]);
            }
            __syncthreads();          // b3: vmcnt(0) — h stores acked at coherence point
            if (tid == 0)             // publish slot t+1 (plain store, packed group line)
                __hip_atomic_store(&flags[gx * 32 + rk], t + 1,
                                   __ATOMIC_RELAXED, __HIP_MEMORY_SCOPE_AGENT);
            if (dt == 7) {
                // Flush 8 buffered h outputs AFTER the flag: HBM acks drain
                // during the next poll, off the critical path.
                #pragma unroll
                for (int j = 0; j < 8; ++j)
                    __builtin_nontemporal_store(hreg[j], &out[((size_t)bbg * TT + t0 + j) * HH + gdim]);
            }
        }
    }
}

extern "C" void kernel_launch(void* const* d_in, const int* in_sizes, int n_in,
                              void* d_out, int out_size, void* d_ws, size_t ws_size,
                              hipStream_t stream)
{
    const float* X    = (const float*)d_in[0];
    const int*   lens = (const int*)d_in[1];
    const float* c0   = (const float*)d_in[2];
    const float* h0   = (const float*)d_in[3];
    const float* Wi   = (const float*)d_in[4];
    const float* Wh   = (const float*)d_in[5];
    const float* bias = (const float*)d_in[6];
    float* out = (float*)d_out;

    // ws layout: xp bf16 [B][H][T/8][4][8] (134.2 MB) | hbuf ring bf16 [T+1][B*H]
    //            (33.6 MB) | flags int[64] packed (group 0: [0..31], group 1: [32..63])
    unsigned short* xp   = (unsigned short*)d_ws;
    unsigned short* hbuf = xp + (size_t)BB * HH * TT * 4;
    int* flags = (int*)(hbuf + (size_t)(TT + 1) * HSLOT);

    // flags = -1: nobody passes the t=0 poll until h0 is published.
    (void)hipMemsetAsync(flags, 0xff, sizeof(int) * NWG, stream);

    xproj_gemm<<<dim3((BB*TT/128) * (G4/128)), dim3(512), 0, stream>>>(X, Wi, xp);

    const unsigned short* xp_c = xp;
    unsigned short* hbuf_p = hbuf;
    int* flags_p = flags;
    void* args[9];
    args[0] = (void*)&xp_c;
    args[1] = (void*)&lens;
    args[2] = (void*)&c0;
    args[3] = (void*)&h0;
    args[4] = (void*)&Wh;
    args[5] = (void*)&bias;
    args[6] = (void*)&out;
    args[7] = (void*)&hbuf_p;
    args[8] = (void*)&flags_p;
    (void)hipLaunchCooperativeKernel((void*)lstm_seq, dim3(NWG), dim3(BLK), args, 0, stream);
}